// Round 1
// baseline (731.089 us; speedup 1.0000x reference)
//
#include <hip/hip_runtime.h>
#include <hip/hip_bf16.h>
#include <cstdint>

typedef __bf16 bf16x8 __attribute__((ext_vector_type(8)));
typedef float  f32x4  __attribute__((ext_vector_type(4)));

static constexpr int B = 8, S = 2048, D = 1024;
static constexpr long BSD = (long)B * S * D;   // 16,777,216
static constexpr long SD  = (long)S * D;       // 2,097,152
static constexpr long SS  = (long)S * S;       // 4,194,304

__device__ __forceinline__ unsigned short f2bf(float f) {
  unsigned u = __float_as_uint(f);
  u += 0x7FFFu + ((u >> 16) & 1u);
  return (unsigned short)(u >> 16);
}
__device__ __forceinline__ float bf2f(unsigned short h) {
  return __uint_as_float(((unsigned)h) << 16);
}

__device__ __forceinline__ void gload16(const void* g, void* l) {
  __builtin_amdgcn_global_load_lds(
      (const __attribute__((address_space(1))) void*)g,
      (__attribute__((address_space(3))) void*)l, 16, 0, 0);
}

// ---------------- prep: xp = x + pos -> bf16 hi/lo ----------------
__global__ __launch_bounds__(256) void prep_x_kernel(
    const float* __restrict__ x, const float* __restrict__ pos,
    unsigned short* __restrict__ xh, unsigned short* __restrict__ xl) {
  long i = ((long)blockIdx.x * 256 + threadIdx.x) * 4;
  float4 xv = *(const float4*)(x + i);
  long p = i & (SD - 1);
  float4 pv = *(const float4*)(pos + p);
  float v[4] = {xv.x + pv.x, xv.y + pv.y, xv.z + pv.z, xv.w + pv.w};
  ushort4 hv, lv;
  unsigned short h;
  h = f2bf(v[0]); hv.x = h; lv.x = f2bf(v[0] - bf2f(h));
  h = f2bf(v[1]); hv.y = h; lv.y = f2bf(v[1] - bf2f(h));
  h = f2bf(v[2]); hv.z = h; lv.z = f2bf(v[2] - bf2f(h));
  h = f2bf(v[3]); hv.w = h; lv.w = f2bf(v[3] - bf2f(h));
  *(ushort4*)(xh + i) = hv;
  *(ushort4*)(xl + i) = lv;
}

// ---------------- prep: weights -> transposed bf16 (hi/lo for Wq,Wk) ----------------
__global__ __launch_bounds__(256) void prep_w_kernel(
    const float* __restrict__ Wq, const float* __restrict__ Wk,
    const float* __restrict__ Wv, const float* __restrict__ Wo,
    unsigned short* __restrict__ qh, unsigned short* __restrict__ ql,
    unsigned short* __restrict__ kh, unsigned short* __restrict__ kl,
    unsigned short* __restrict__ vh, unsigned short* __restrict__ oh) {
  int o = blockIdx.x * 256 + threadIdx.x;      // o = dout*D + din
  int dout = o >> 10, din = o & 1023;
  int src = (din << 10) + dout;
  float q = Wq[src]; unsigned short h = f2bf(q);
  qh[o] = h; ql[o] = f2bf(q - bf2f(h));
  float k = Wk[src]; h = f2bf(k);
  kh[o] = h; kl[o] = f2bf(k - bf2f(h));
  vh[o] = f2bf(Wv[src]);
  oh[o] = f2bf(Wo[src]);
}

// ---------------- generic MFMA GEMM: C[M,N] = A[M,K] * Bt[N,K]^T ----------------
enum { EPI_SPLIT = 0, EPI_VT = 1, EPI_PW = 2, EPI_BF16 = 3, EPI_F32B = 4 };

template<int PRODUCTS, int EPI>
__global__ __launch_bounds__(256, 2) void gemm_kernel(
    const unsigned short* __restrict__ Ah, const unsigned short* __restrict__ Al,
    const unsigned short* __restrict__ Bh, const unsigned short* __restrict__ Bl,
    const float* __restrict__ bias,
    float* __restrict__ outF, unsigned short* __restrict__ outH,
    unsigned short* __restrict__ outL,
    int M, int N, int K, long sA, long sB, long sC)
{
  constexpr int BM = 128, BN = 128, BK = 64;
  constexpr int NT = (PRODUCTS == 3) ? 4 : 2;
  __shared__ __align__(16) unsigned short smem[NT * BM * BK];
  unsigned short* Ash = smem;
  unsigned short* Bsh = smem + BM * BK;
  unsigned short* Asl = smem + 2 * BM * BK;
  unsigned short* Bsl = smem + 3 * BM * BK;

  const int tid = threadIdx.x;
  const int z = blockIdx.z;
  const long arow0 = (long)blockIdx.y * BM;
  const long brow0 = (long)blockIdx.x * BN;
  const unsigned short* Agh = Ah + (long)z * sA + arow0 * K;
  const unsigned short* Bgh = Bh + (long)z * sB + brow0 * K;
  const unsigned short* Agl = (PRODUCTS == 3) ? (Al + (long)z * sA + arow0 * K) : nullptr;
  const unsigned short* Bgl = (PRODUCTS == 3) ? (Bl + (long)z * sB + brow0 * K) : nullptr;

  const int lane = tid & 63;
  const int wr = ((tid >> 6) >> 1) * 64;   // wave row offset in tile
  const int wc = ((tid >> 6) & 1) * 64;    // wave col offset
  const int lrow = lane & 15;
  const int lk = (lane >> 4) * 8;

  f32x4 acc[4][4] = {};

  for (int k0 = 0; k0 < K; k0 += BK) {
    #pragma unroll
    for (int rr = 0; rr < 4; ++rr) {
      const int chunk = rr * 256 + tid;     // 0..1023
      const int row = chunk >> 3;           // 0..127
      const int col = (chunk & 7) * 8;      // 0..56
      gload16(Agh + (long)row * K + k0 + col, Ash + chunk * 8);
      gload16(Bgh + (long)row * K + k0 + col, Bsh + chunk * 8);
      if (PRODUCTS == 3) {
        gload16(Agl + (long)row * K + k0 + col, Asl + chunk * 8);
        gload16(Bgl + (long)row * K + k0 + col, Bsl + chunk * 8);
      }
    }
    __syncthreads();
    #pragma unroll
    for (int kk = 0; kk < 2; ++kk) {
      bf16x8 a_h[4], a_l[4];
      #pragma unroll
      for (int i = 0; i < 4; ++i) {
        a_h[i] = *(const bf16x8*)&Ash[(wr + i * 16 + lrow) * BK + kk * 32 + lk];
        if (PRODUCTS == 3)
          a_l[i] = *(const bf16x8*)&Asl[(wr + i * 16 + lrow) * BK + kk * 32 + lk];
      }
      #pragma unroll
      for (int j = 0; j < 4; ++j) {
        const bf16x8 b_h = *(const bf16x8*)&Bsh[(wc + j * 16 + lrow) * BK + kk * 32 + lk];
        bf16x8 b_l = {};
        if (PRODUCTS == 3)
          b_l = *(const bf16x8*)&Bsl[(wc + j * 16 + lrow) * BK + kk * 32 + lk];
        #pragma unroll
        for (int i = 0; i < 4; ++i) {
          acc[i][j] = __builtin_amdgcn_mfma_f32_16x16x32_bf16(a_h[i], b_h, acc[i][j], 0, 0, 0);
          if (PRODUCTS == 3) {
            acc[i][j] = __builtin_amdgcn_mfma_f32_16x16x32_bf16(a_h[i], b_l, acc[i][j], 0, 0, 0);
            acc[i][j] = __builtin_amdgcn_mfma_f32_16x16x32_bf16(a_l[i], b_h, acc[i][j], 0, 0, 0);
          }
        }
      }
    }
    __syncthreads();
  }

  // epilogue: C/D layout col = lane&15, row = (lane>>4)*4 + r  [m89-verified]
  const int rbase = (int)arow0 + wr + (lane >> 4) * 4;
  const int cbase = (int)brow0 + wc + lrow;
  #pragma unroll
  for (int j = 0; j < 4; ++j) {
    const int col = cbase + j * 16;
    float bv = 0.0f;
    if (EPI == EPI_SPLIT || EPI == EPI_VT || EPI == EPI_F32B) bv = bias[col];
    #pragma unroll
    for (int i = 0; i < 4; ++i) {
      #pragma unroll
      for (int r = 0; r < 4; ++r) {
        const int row = rbase + i * 16 + r;
        float v = acc[i][j][r];
        if (EPI == EPI_SPLIT) {
          v += bv;
          unsigned short h = f2bf(v);
          long idx = (long)row * N + col;
          outH[idx] = h;
          outL[idx] = f2bf(v - bf2f(h));
        } else if (EPI == EPI_VT) {
          v += bv;
          int bb = row >> 11;            // row / S
          int t = row & (S - 1);
          outH[(long)bb * SD + (long)col * S + t] = f2bf(v);
        } else if (EPI == EPI_PW) {
          int dd = row - col; if (dd < 0) dd = -dd;
          float dist = (float)dd * (1.0f / 2048.0f);
          float pw = (1.0f + 1.5f * expf(-2.0f * dist)) / 2.5f;
          v = v * (1.0f / 32.0f) * pw;
          outF[(long)z * sC + (long)row * N + col] = v;
        } else if (EPI == EPI_BF16) {
          outH[(long)z * sC + (long)row * N + col] = f2bf(v);
        } else {  // EPI_F32B
          outF[(long)row * N + col] = v + bv;
        }
      }
    }
  }
}

// ---------------- row softmax over 2048, write f32 (in-place) + bf16 copy ----------------
__global__ __launch_bounds__(256) void softmax_kernel(
    float* __restrict__ attn, unsigned short* __restrict__ abf) {
  const long base = (long)blockIdx.x * S + threadIdx.x * 4;
  const int tid = threadIdx.x;
  float4 v0 = *(const float4*)(attn + base);
  float4 v1 = *(const float4*)(attn + base + 1024);
  float m = fmaxf(fmaxf(fmaxf(v0.x, v0.y), fmaxf(v0.z, v0.w)),
                  fmaxf(fmaxf(v1.x, v1.y), fmaxf(v1.z, v1.w)));
  #pragma unroll
  for (int sh = 1; sh < 64; sh <<= 1) m = fmaxf(m, __shfl_xor(m, sh));
  __shared__ float red[8];
  const int w = tid >> 6;
  if ((tid & 63) == 0) red[w] = m;
  __syncthreads();
  m = fmaxf(fmaxf(red[0], red[1]), fmaxf(red[2], red[3]));
  float e[8];
  e[0] = expf(v0.x - m); e[1] = expf(v0.y - m);
  e[2] = expf(v0.z - m); e[3] = expf(v0.w - m);
  e[4] = expf(v1.x - m); e[5] = expf(v1.y - m);
  e[6] = expf(v1.z - m); e[7] = expf(v1.w - m);
  float s8 = ((e[0] + e[1]) + (e[2] + e[3])) + ((e[4] + e[5]) + (e[6] + e[7]));
  #pragma unroll
  for (int sh = 1; sh < 64; sh <<= 1) s8 += __shfl_xor(s8, sh);
  if ((tid & 63) == 0) red[4 + w] = s8;
  __syncthreads();
  const float inv = 1.0f / ((red[4] + red[5]) + (red[6] + red[7]));
  float4 o0 = make_float4(e[0] * inv, e[1] * inv, e[2] * inv, e[3] * inv);
  float4 o1 = make_float4(e[4] * inv, e[5] * inv, e[6] * inv, e[7] * inv);
  *(float4*)(attn + base) = o0;
  *(float4*)(attn + base + 1024) = o1;
  ushort4 b0, b1;
  b0.x = f2bf(o0.x); b0.y = f2bf(o0.y); b0.z = f2bf(o0.z); b0.w = f2bf(o0.w);
  b1.x = f2bf(o1.x); b1.y = f2bf(o1.y); b1.z = f2bf(o1.z); b1.w = f2bf(o1.w);
  *(ushort4*)(abf + base) = b0;
  *(ushort4*)(abf + base + 1024) = b1;
}

extern "C" void kernel_launch(void* const* d_in, const int* in_sizes, int n_in,
                              void* d_out, int out_size, void* d_ws, size_t ws_size,
                              hipStream_t stream) {
  const float* x   = (const float*)d_in[0];
  const float* pos = (const float*)d_in[1];
  const float* Wq  = (const float*)d_in[2];
  const float* bq  = (const float*)d_in[3];
  const float* Wk  = (const float*)d_in[4];
  const float* bk  = (const float*)d_in[5];
  const float* Wv  = (const float*)d_in[6];
  const float* bv  = (const float*)d_in[7];
  const float* Wo  = (const float*)d_in[8];
  const float* bo  = (const float*)d_in[9];

  float* outp  = (float*)d_out;          // [B,S,D] f32
  float* attnp = outp + BSD;             // [B,S,S] f32 (also scores scratch)

  // workspace layout (172 MB peak)
  unsigned short* wqh = (unsigned short*)d_ws;
  unsigned short* wql = wqh + (long)D * D;
  unsigned short* wkh = wql + (long)D * D;
  unsigned short* wkl = wkh + (long)D * D;
  unsigned short* wvh = wkl + (long)D * D;
  unsigned short* woh = wvh + (long)D * D;
  unsigned short* qh  = woh + (long)D * D;   // [B*S, D] hi
  unsigned short* ql  = qh + BSD;
  unsigned short* kh  = ql + BSD;
  unsigned short* kl  = kh + BSD;
  unsigned short* vt  = kl + BSD;            // [B][D][S] bf16
  unsigned short* abf = qh;                  // reuse Q hi/lo region after scores
  unsigned short* hbf = kh;                  // reuse K hi region after scores

  // xp hi/lo live in the (not-yet-written) attn region of d_out
  unsigned short* xph = (unsigned short*)attnp;
  unsigned short* xpl = xph + BSD;

  dim3 blk(256);
  prep_w_kernel<<<dim3((D * D) / 256), blk, 0, stream>>>(Wq, Wk, Wv, Wo,
                                                         wqh, wql, wkh, wkl, wvh, woh);
  prep_x_kernel<<<dim3((int)(BSD / 1024)), blk, 0, stream>>>(x, pos, xph, xpl);

  dim3 gProj(D / 128, (B * S) / 128, 1);   // (8,128,1)
  gemm_kernel<3, EPI_SPLIT><<<gProj, blk, 0, stream>>>(
      xph, xpl, wqh, wql, bq, nullptr, qh, ql, B * S, D, D, 0, 0, 0);
  gemm_kernel<3, EPI_SPLIT><<<gProj, blk, 0, stream>>>(
      xph, xpl, wkh, wkl, bk, nullptr, kh, kl, B * S, D, D, 0, 0, 0);
  gemm_kernel<1, EPI_VT><<<gProj, blk, 0, stream>>>(
      xph, nullptr, wvh, nullptr, bv, nullptr, vt, nullptr, B * S, D, D, 0, 0, 0);

  dim3 gScore(S / 128, S / 128, B);        // (16,16,8)
  gemm_kernel<3, EPI_PW><<<gScore, blk, 0, stream>>>(
      qh, ql, kh, kl, nullptr, attnp, nullptr, nullptr, S, S, D, SD, SD, SS);

  softmax_kernel<<<dim3(B * S), blk, 0, stream>>>(attnp, abf);

  dim3 gPV(D / 128, S / 128, B);           // (8,16,8)
  gemm_kernel<1, EPI_BF16><<<gPV, blk, 0, stream>>>(
      abf, nullptr, vt, nullptr, nullptr, nullptr, hbf, nullptr, S, D, S, SS, SD, SD);

  dim3 gOut(D / 128, (B * S) / 128, 1);
  gemm_kernel<1, EPI_F32B><<<gOut, blk, 0, stream>>>(
      hbf, nullptr, woh, nullptr, bo, outp, nullptr, nullptr, B * S, D, D, 0, 0, 0);
}

// Round 2
// 499.958 us; speedup vs baseline: 1.4623x; 1.4623x over previous
//
#include <hip/hip_runtime.h>
#include <hip/hip_bf16.h>
#include <cstdint>

typedef _Float16 f16x8 __attribute__((ext_vector_type(8)));
typedef _Float16 f16x4 __attribute__((ext_vector_type(4)));
typedef float    f32x4 __attribute__((ext_vector_type(4)));

static constexpr int B = 8, S = 2048, D = 1024;
static constexpr long BSD = (long)B * S * D;   // 16,777,216
static constexpr long SD  = (long)S * D;       // 2,097,152
static constexpr long SS  = (long)S * S;       // 4,194,304

__device__ __forceinline__ void gload16(const void* g, void* l) {
  __builtin_amdgcn_global_load_lds(
      (const __attribute__((address_space(1))) void*)g,
      (__attribute__((address_space(3))) void*)l, 16, 0, 0);
}

// ---------------- prep: xp = x + pos -> f16 ----------------
__global__ __launch_bounds__(256) void prep_x_kernel(
    const float* __restrict__ x, const float* __restrict__ pos,
    _Float16* __restrict__ xh) {
  long i = ((long)blockIdx.x * 256 + threadIdx.x) * 4;
  float4 xv = *(const float4*)(x + i);
  long p = i & (SD - 1);
  float4 pv = *(const float4*)(pos + p);
  f16x4 h;
  h.x = (_Float16)(xv.x + pv.x);
  h.y = (_Float16)(xv.y + pv.y);
  h.z = (_Float16)(xv.z + pv.z);
  h.w = (_Float16)(xv.w + pv.w);
  *(f16x4*)(xh + i) = h;
}

// ---------------- prep: weights -> transposed f16 ----------------
__global__ __launch_bounds__(256) void prep_w_kernel(
    const float* __restrict__ Wq, const float* __restrict__ Wk,
    const float* __restrict__ Wv, const float* __restrict__ Wo,
    _Float16* __restrict__ qh, _Float16* __restrict__ kh,
    _Float16* __restrict__ vh, _Float16* __restrict__ oh) {
  int o = blockIdx.x * 256 + threadIdx.x;      // o = dout*D + din
  int dout = o >> 10, din = o & 1023;
  int src = (din << 10) + dout;
  qh[o] = (_Float16)Wq[src];
  kh[o] = (_Float16)Wk[src];
  vh[o] = (_Float16)Wv[src];
  oh[o] = (_Float16)Wo[src];
}

// ---------------- generic MFMA GEMM: C[M,N] = A[M,K] * Bt[N,K]^T ----------------
enum { EPI_F16B = 0, EPI_VT = 1, EPI_PW = 2, EPI_F16 = 3, EPI_F32B = 4 };

template<int EPI>
__global__ __launch_bounds__(256, 4) void gemm_kernel(
    const _Float16* __restrict__ A, const _Float16* __restrict__ Bt,
    const float* __restrict__ bias,
    float* __restrict__ outF, _Float16* __restrict__ outH,
    int M, int N, int K, long sA, long sB, long sC)
{
  constexpr int BM = 128, BN = 128, BK = 64;
  __shared__ __align__(16) _Float16 smem[2 * BM * BK];
  _Float16* Ash = smem;
  _Float16* Bsh = smem + BM * BK;

  const int tid = threadIdx.x;
  const int z = blockIdx.z;
  const long arow0 = (long)blockIdx.y * BM;
  const long brow0 = (long)blockIdx.x * BN;
  const _Float16* Ag = A + (long)z * sA + arow0 * K;
  const _Float16* Bg = Bt + (long)z * sB + brow0 * K;

  const int lane = tid & 63;
  const int wr = ((tid >> 6) >> 1) * 64;   // wave row offset in tile
  const int wc = ((tid >> 6) & 1) * 64;    // wave col offset
  const int lrow = lane & 15;
  const int lk = (lane >> 4) * 8;

  f32x4 acc[4][4] = {};

  for (int k0 = 0; k0 < K; k0 += BK) {
    #pragma unroll
    for (int rr = 0; rr < 4; ++rr) {
      const int chunk = rr * 256 + tid;     // 0..1023
      const int row = chunk >> 3;           // 0..127
      const int col = (chunk & 7) * 8;      // 0..56
      gload16(Ag + (long)row * K + k0 + col, Ash + chunk * 8);
      gload16(Bg + (long)row * K + k0 + col, Bsh + chunk * 8);
    }
    __syncthreads();
    #pragma unroll
    for (int kk = 0; kk < 2; ++kk) {
      f16x8 a_h[4];
      #pragma unroll
      for (int i = 0; i < 4; ++i)
        a_h[i] = *(const f16x8*)&Ash[(wr + i * 16 + lrow) * BK + kk * 32 + lk];
      #pragma unroll
      for (int j = 0; j < 4; ++j) {
        const f16x8 b_h = *(const f16x8*)&Bsh[(wc + j * 16 + lrow) * BK + kk * 32 + lk];
        #pragma unroll
        for (int i = 0; i < 4; ++i)
          acc[i][j] = __builtin_amdgcn_mfma_f32_16x16x32_f16(a_h[i], b_h, acc[i][j], 0, 0, 0);
      }
    }
    __syncthreads();
  }

  // epilogue: C/D layout col = lane&15, row = (lane>>4)*4 + r  [m89-verified]
  const int rbase = (int)arow0 + wr + (lane >> 4) * 4;
  const int cbase = (int)brow0 + wc + lrow;
  #pragma unroll
  for (int j = 0; j < 4; ++j) {
    const int col = cbase + j * 16;
    float bv = 0.0f;
    if (EPI == EPI_F16B || EPI == EPI_VT || EPI == EPI_F32B) bv = bias[col];
    #pragma unroll
    for (int i = 0; i < 4; ++i) {
      #pragma unroll
      for (int r = 0; r < 4; ++r) {
        const int row = rbase + i * 16 + r;
        float v = acc[i][j][r];
        if (EPI == EPI_F16B) {
          outH[(long)row * N + col] = (_Float16)(v + bv);
        } else if (EPI == EPI_VT) {
          int bb = row >> 11;            // row / S
          int t = row & (S - 1);
          outH[(long)bb * SD + (long)col * S + t] = (_Float16)(v + bv);
        } else if (EPI == EPI_PW) {
          int dd = row - col; if (dd < 0) dd = -dd;
          float dist = (float)dd * (1.0f / 2048.0f);
          float pw = (1.0f + 1.5f * expf(-2.0f * dist)) / 2.5f;
          outF[(long)z * sC + (long)row * N + col] = v * (1.0f / 32.0f) * pw;
        } else if (EPI == EPI_F16) {
          outH[(long)z * sC + (long)row * N + col] = (_Float16)v;
        } else {  // EPI_F32B
          outF[(long)row * N + col] = v + bv;
        }
      }
    }
  }
}

// ---------------- row softmax over 2048, f32 in-place + f16 copy ----------------
__global__ __launch_bounds__(256) void softmax_kernel(
    float* __restrict__ attn, _Float16* __restrict__ abf) {
  const long base = (long)blockIdx.x * S + threadIdx.x * 4;
  const int tid = threadIdx.x;
  float4 v0 = *(const float4*)(attn + base);
  float4 v1 = *(const float4*)(attn + base + 1024);
  float m = fmaxf(fmaxf(fmaxf(v0.x, v0.y), fmaxf(v0.z, v0.w)),
                  fmaxf(fmaxf(v1.x, v1.y), fmaxf(v1.z, v1.w)));
  #pragma unroll
  for (int sh = 1; sh < 64; sh <<= 1) m = fmaxf(m, __shfl_xor(m, sh));
  __shared__ float red[8];
  const int w = tid >> 6;
  if ((tid & 63) == 0) red[w] = m;
  __syncthreads();
  m = fmaxf(fmaxf(red[0], red[1]), fmaxf(red[2], red[3]));
  float e[8];
  e[0] = expf(v0.x - m); e[1] = expf(v0.y - m);
  e[2] = expf(v0.z - m); e[3] = expf(v0.w - m);
  e[4] = expf(v1.x - m); e[5] = expf(v1.y - m);
  e[6] = expf(v1.z - m); e[7] = expf(v1.w - m);
  float s8 = ((e[0] + e[1]) + (e[2] + e[3])) + ((e[4] + e[5]) + (e[6] + e[7]));
  #pragma unroll
  for (int sh = 1; sh < 64; sh <<= 1) s8 += __shfl_xor(s8, sh);
  if ((tid & 63) == 0) red[4 + w] = s8;
  __syncthreads();
  const float inv = 1.0f / ((red[4] + red[5]) + (red[6] + red[7]));
  float4 o0 = make_float4(e[0] * inv, e[1] * inv, e[2] * inv, e[3] * inv);
  float4 o1 = make_float4(e[4] * inv, e[5] * inv, e[6] * inv, e[7] * inv);
  *(float4*)(attn + base) = o0;
  *(float4*)(attn + base + 1024) = o1;
  f16x4 b0, b1;
  b0.x = (_Float16)o0.x; b0.y = (_Float16)o0.y;
  b0.z = (_Float16)o0.z; b0.w = (_Float16)o0.w;
  b1.x = (_Float16)o1.x; b1.y = (_Float16)o1.y;
  b1.z = (_Float16)o1.z; b1.w = (_Float16)o1.w;
  *(f16x4*)(abf + base) = b0;
  *(f16x4*)(abf + base + 1024) = b1;
}

extern "C" void kernel_launch(void* const* d_in, const int* in_sizes, int n_in,
                              void* d_out, int out_size, void* d_ws, size_t ws_size,
                              hipStream_t stream) {
  const float* x   = (const float*)d_in[0];
  const float* pos = (const float*)d_in[1];
  const float* Wq  = (const float*)d_in[2];
  const float* bq  = (const float*)d_in[3];
  const float* Wk  = (const float*)d_in[4];
  const float* bk  = (const float*)d_in[5];
  const float* Wv  = (const float*)d_in[6];
  const float* bv  = (const float*)d_in[7];
  const float* Wo  = (const float*)d_in[8];
  const float* bo  = (const float*)d_in[9];

  float* outp  = (float*)d_out;          // [B,S,D] f32
  float* attnp = outp + BSD;             // [B,S,S] f32 (also scores scratch)

  // workspace layout (~142 MB peak)
  _Float16* wqh = (_Float16*)d_ws;
  _Float16* wkh = wqh + (long)D * D;
  _Float16* wvh = wkh + (long)D * D;
  _Float16* woh = wvh + (long)D * D;
  _Float16* qh  = woh + (long)D * D;   // [B*S, D]
  _Float16* kh  = qh + BSD;            // [B*S, D]
  _Float16* vt  = kh + BSD;            // [B][D][S]
  _Float16* hbf = vt + BSD;            // [B*S, D] PV output
  _Float16* abf = qh;                  // f16 attn reuses q+k region (67 MB)

  // xp f16 lives in the (not-yet-written) attn region of d_out
  _Float16* xph = (_Float16*)attnp;

  dim3 blk(256);
  prep_w_kernel<<<dim3((D * D) / 256), blk, 0, stream>>>(Wq, Wk, Wv, Wo,
                                                         wqh, wkh, wvh, woh);
  prep_x_kernel<<<dim3((int)(BSD / 1024)), blk, 0, stream>>>(x, pos, xph);

  dim3 gProj(D / 128, (B * S) / 128, 1);   // (8,128,1)
  gemm_kernel<EPI_F16B><<<gProj, blk, 0, stream>>>(
      xph, wqh, bq, nullptr, qh, B * S, D, D, 0, 0, 0);
  gemm_kernel<EPI_F16B><<<gProj, blk, 0, stream>>>(
      xph, wkh, bk, nullptr, kh, B * S, D, D, 0, 0, 0);
  gemm_kernel<EPI_VT><<<gProj, blk, 0, stream>>>(
      xph, wvh, bv, nullptr, vt, B * S, D, D, 0, 0, 0);

  dim3 gScore(S / 128, S / 128, B);        // (16,16,8)
  gemm_kernel<EPI_PW><<<gScore, blk, 0, stream>>>(
      qh, kh, nullptr, attnp, nullptr, S, S, D, SD, SD, SS);

  softmax_kernel<<<dim3(B * S), blk, 0, stream>>>(attnp, abf);

  dim3 gPV(D / 128, S / 128, B);           // (8,16,8)
  gemm_kernel<EPI_F16><<<gPV, blk, 0, stream>>>(
      abf, vt, nullptr, nullptr, hbf, S, D, S, SS, SD, SD);

  dim3 gOut(D / 128, (B * S) / 128, 1);
  gemm_kernel<EPI_F32B><<<gOut, blk, 0, stream>>>(
      hbf, woh, bo, outp, nullptr, B * S, D, D, 0, 0, 0);
}